// Round 14
// baseline (80.188 us; speedup 1.0000x reference)
//
#include <hip/hip_runtime.h>
#include <hip/hip_bf16.h>
#include <hip/hip_fp16.h>

#define BDIM    128   // batch size, fixed by problem
#define NGROUPS 2     // batch groups (64 batches each), one per XCD quad
#define GCOLS   64    // batch columns per group
#define ROWB    (GCOLS * 2)            // bytes per xTh row = 128 (one L2 line)
#define EBLK    2048  // edge-kernel blocks (divisible by 8)
#define RANKS   (EBLK / NGROUPS)       // blocks per group = 1024
#define WPG     (RANKS * 4)            // waves per group = 4096
#define S1BLK   (NGROUPS * 8)          // stage-1 edge-reduce blocks = 16
#define HBLK2   8     // stage-1 h-reduce blocks
#define RPS     (RANKS / 8)            // ranks per stage-1 block = 128
#define TPAD    132   // tile row stride (floats): 16B-aligned, banks <=4-way

// ---------------------------------------------------------------------------
// Kernel 1: transpose+convert x (B=128,N) f32 -> xTh[g][N][64] fp16 slices.
// h-term now FUSED INTO THE READ PHASE: each thread accumulates
// x[b,n..n+3]·h[n..n+3] from the float4 registers (no second LDS sweep),
// shuffle-reduced across the 16 n-quad lanes. One barrier total.
// ---------------------------------------------------------------------------
__global__ __launch_bounds__(256) void transpose_h_kernel(
    const float* __restrict__ x, const float* __restrict__ h,
    __half* __restrict__ xTh, float* __restrict__ hp, int N) {
  __shared__ float tile[64 * TPAD];
  const int tid = threadIdx.x;
  const int n0  = blockIdx.x * 64;

  const int c     = tid & 15;
  const int b0    = tid >> 4;
  const int nbase = n0 + 4 * c;

  // guarded h quad for this thread's n-range
  float4 hv;
  if (nbase + 3 < N) {
    hv = *(const float4*)&h[nbase];
  } else {
    hv.x = (nbase + 0 < N) ? h[nbase + 0] : 0.f;
    hv.y = (nbase + 1 < N) ? h[nbase + 1] : 0.f;
    hv.z = (nbase + 2 < N) ? h[nbase + 2] : 0.f;
    hv.w = (nbase + 3 < N) ? h[nbase + 3] : 0.f;
  }

  float hacc[8];
#pragma unroll
  for (int p = 0; p < 8; ++p) hacc[p] = 0.f;

#pragma unroll
  for (int p = 0; p < 8; ++p) {
    const int b = b0 + 16 * p;
    float4 v;
    if (nbase + 3 < N) {
      v = *(const float4*)&x[(size_t)b * N + nbase];
    } else {
      v.x = (nbase + 0 < N) ? x[(size_t)b * N + nbase + 0] : 0.f;
      v.y = (nbase + 1 < N) ? x[(size_t)b * N + nbase + 1] : 0.f;
      v.z = (nbase + 2 < N) ? x[(size_t)b * N + nbase + 2] : 0.f;
      v.w = (nbase + 3 < N) ? x[(size_t)b * N + nbase + 3] : 0.f;
    }
    tile[(4 * c + 0) * TPAD + b] = v.x;
    tile[(4 * c + 1) * TPAD + b] = v.y;
    tile[(4 * c + 2) * TPAD + b] = v.z;
    tile[(4 * c + 3) * TPAD + b] = v.w;
    hacc[p] = fmaf(v.x, hv.x, fmaf(v.y, hv.y, fmaf(v.z, hv.z,
              fmaf(v.w, hv.w, hacc[p]))));
  }

  // reduce hacc across the 16 c-lanes of each b0 group (lanes are contiguous)
#pragma unroll
  for (int off = 1; off < 16; off <<= 1)
#pragma unroll
    for (int p = 0; p < 8; ++p) hacc[p] += __shfl_xor(hacc[p], off);

  if ((tid & 15) == 0) {
#pragma unroll
    for (int p = 0; p < 8; ++p)
      hp[(size_t)blockIdx.x * BDIM + b0 + 16 * p] = hacc[p];
  }
  __syncthreads();

  // store: thread = (oct, g2, r0); 2x ds_read_b128 + pack + 16B store, 4 passes
  const int oct = tid & 7;
  const int g2  = (tid >> 3) & 1;
  const int r0  = tid >> 4;
#pragma unroll
  for (int p = 0; p < 4; ++p) {
    const int nl = r0 + 16 * p;
    const int n  = n0 + nl;
    if (n < N) {
      const float* src = &tile[nl * TPAD + g2 * GCOLS + oct * 8];
      const float4 lo = *(const float4*)(src);
      const float4 hi = *(const float4*)(src + 4);
      int4 outv;
      outv.x = __builtin_bit_cast(int, __floats2half2_rn(lo.x, lo.y));
      outv.y = __builtin_bit_cast(int, __floats2half2_rn(lo.z, lo.w));
      outv.z = __builtin_bit_cast(int, __floats2half2_rn(hi.x, hi.y));
      outv.w = __builtin_bit_cast(int, __floats2half2_rn(hi.z, hi.w));
      *(int4*)(xTh + ((size_t)g2 * N + n) * GCOLS + oct * 8) = outv;
    }
  }
}

// ---------------------------------------------------------------------------
// 8-column fp16 product with v_fma_mix_f32 accumulate.
// ---------------------------------------------------------------------------
__device__ __forceinline__ void fma8mix(float* acc, int4 vi, int4 vj, float Jv) {
  const int wi[4] = {vi.x, vi.y, vi.z, vi.w};
  const int wj[4] = {vj.x, vj.y, vj.z, vj.w};
#pragma unroll
  for (int w = 0; w < 4; ++w) {
    const __half2 hi = __builtin_bit_cast(__half2, wi[w]);
    const __half2 hj = __builtin_bit_cast(__half2, wj[w]);
    const int p = __builtin_bit_cast(int, __hmul2(hi, hj));
    asm("v_fma_mix_f32 %0, %1, %2, %0 op_sel_hi:[1,0,0]"
        : "+v"(acc[2 * w]) : "v"(p), "v"(Jv));
    asm("v_fma_mix_f32 %0, %1, %2, %0 op_sel:[1,0,0] op_sel_hi:[1,0,0]"
        : "+v"(acc[2 * w + 1]) : "v"(p), "v"(Jv));
  }
}

// ---------------------------------------------------------------------------
// Kernel 2: edge interactions — R13 config, unchanged (at the measured
// random-128B-line service wall: ~5.1 cyc/line/CU). Barrier-free waves,
// shuffle-distributed indices, pinned 16-gather cluster.
// ---------------------------------------------------------------------------
__global__ __launch_bounds__(256, 4) void edge_kernel(
    const __half* __restrict__ xTh, const float* __restrict__ J,
    const int* __restrict__ ei, const int* __restrict__ ej,
    float* __restrict__ P, int E, int N) {
  const int tid  = threadIdx.x;
  const int g    = (blockIdx.x & 7) >> 2;
  const int rank = (blockIdx.x >> 3) * 4 + (blockIdx.x & 3);
  const int wave = tid >> 6;
  const int lane = tid & 63;
  const int k    = lane >> 3;          // edge sub-index 0..7
  const char* xgl = (const char*)xTh + (size_t)g * N * ROWB + (lane & 7) * 16;

  const int  wi   = rank * 4 + wave;          // wave id within group [0, WPG)
  const long TC   = (E + 63) >> 6;            // total 64-edge chunks
  int base = (int)((long)wi * TC / WPG) * 64;
  const int bend = (int)((long)(wi + 1) * TC / WPG) * 64;

  float acc[8] = {0.f, 0.f, 0.f, 0.f, 0.f, 0.f, 0.f, 0.f};

  int ri = 0, rj = 0;
  float rJ = 0.f;
  if (base < bend) {
    const int e  = base + lane;
    const int ec = min(e, E - 1);
    ri = ei[ec]; rj = ej[ec]; rJ = (e < E) ? J[ec] : 0.f;
  }

  for (; base < bend; base += 64) {
    const int ci = ri, cj = rj;
    const float cJ = rJ;
    {
      const int nb = base + 64;
      if (nb < bend) {
        const int e  = nb + lane;
        const int ec = min(e, E - 1);
        ri = ei[ec]; rj = ej[ec]; rJ = (e < E) ? J[ec] : 0.f;
      }
    }

    const int   i0 = __shfl(ci, 0 * 8 + k), j0 = __shfl(cj, 0 * 8 + k);
    const int   i1 = __shfl(ci, 1 * 8 + k), j1 = __shfl(cj, 1 * 8 + k);
    const int   i2 = __shfl(ci, 2 * 8 + k), j2 = __shfl(cj, 2 * 8 + k);
    const int   i3 = __shfl(ci, 3 * 8 + k), j3 = __shfl(cj, 3 * 8 + k);
    const int   i4 = __shfl(ci, 4 * 8 + k), j4 = __shfl(cj, 4 * 8 + k);
    const int   i5 = __shfl(ci, 5 * 8 + k), j5 = __shfl(cj, 5 * 8 + k);
    const int   i6 = __shfl(ci, 6 * 8 + k), j6 = __shfl(cj, 6 * 8 + k);
    const int   i7 = __shfl(ci, 7 * 8 + k), j7 = __shfl(cj, 7 * 8 + k);
    const float J0 = __shfl(cJ, 0 * 8 + k), J1 = __shfl(cJ, 1 * 8 + k);
    const float J2 = __shfl(cJ, 2 * 8 + k), J3 = __shfl(cJ, 3 * 8 + k);
    const float J4 = __shfl(cJ, 4 * 8 + k), J5 = __shfl(cJ, 5 * 8 + k);
    const float J6 = __shfl(cJ, 6 * 8 + k), J7 = __shfl(cJ, 7 * 8 + k);

    const int4 vi0 = *(const int4*)(xgl + (unsigned)i0 * ROWB);
    const int4 vj0 = *(const int4*)(xgl + (unsigned)j0 * ROWB);
    const int4 vi1 = *(const int4*)(xgl + (unsigned)i1 * ROWB);
    const int4 vj1 = *(const int4*)(xgl + (unsigned)j1 * ROWB);
    const int4 vi2 = *(const int4*)(xgl + (unsigned)i2 * ROWB);
    const int4 vj2 = *(const int4*)(xgl + (unsigned)j2 * ROWB);
    const int4 vi3 = *(const int4*)(xgl + (unsigned)i3 * ROWB);
    const int4 vj3 = *(const int4*)(xgl + (unsigned)j3 * ROWB);
    const int4 vi4 = *(const int4*)(xgl + (unsigned)i4 * ROWB);
    const int4 vj4 = *(const int4*)(xgl + (unsigned)j4 * ROWB);
    const int4 vi5 = *(const int4*)(xgl + (unsigned)i5 * ROWB);
    const int4 vj5 = *(const int4*)(xgl + (unsigned)j5 * ROWB);
    const int4 vi6 = *(const int4*)(xgl + (unsigned)i6 * ROWB);
    const int4 vj6 = *(const int4*)(xgl + (unsigned)j6 * ROWB);
    const int4 vi7 = *(const int4*)(xgl + (unsigned)i7 * ROWB);
    const int4 vj7 = *(const int4*)(xgl + (unsigned)j7 * ROWB);
    __builtin_amdgcn_sched_barrier(0);
    fma8mix(acc, vi0, vj0, J0);
    fma8mix(acc, vi1, vj1, J1);
    fma8mix(acc, vi2, vj2, J2);
    fma8mix(acc, vi3, vj3, J3);
    fma8mix(acc, vi4, vj4, J4);
    fma8mix(acc, vi5, vj5, J5);
    fma8mix(acc, vi6, vj6, J6);
    fma8mix(acc, vi7, vj7, J7);
  }

#pragma unroll
  for (int off = 8; off < 64; off <<= 1)
#pragma unroll
    for (int w = 0; w < 8; ++w) acc[w] += __shfl_xor(acc[w], off);

  __shared__ float red[4][GCOLS];
  if (lane < 8)
#pragma unroll
    for (int w = 0; w < 8; ++w) red[wave][lane * 8 + w] = acc[w];
  __syncthreads();
  if (tid < GCOLS) {
    const float s = red[0][tid] + red[1][tid] + red[2][tid] + red[3][tid];
    P[((size_t)g * RANKS + rank) * GCOLS + tid] = s;
  }
}

// ---------------------------------------------------------------------------
// Kernel 3: stage-1 reduce. Blocks [0,16): edge partials (g,s) sum 128 rank
// rows -> P2. Blocks [16,24): h partials, block s sums rows r%8==s -> hp2.
// ---------------------------------------------------------------------------
__global__ __launch_bounds__(256) void reduce1_kernel(
    const float* __restrict__ P, const float* __restrict__ hp,
    float* __restrict__ P2, float* __restrict__ hp2, int hrows) {
  __shared__ float red[4][GCOLS];
  __shared__ float redh[2][BDIM];
  if (blockIdx.x < S1BLK) {
    const int g  = blockIdx.x >> 3;
    const int s  = blockIdx.x & 7;
    const int rl = threadIdx.x >> 6;  // 0..3
    const int c  = threadIdx.x & 63;
    float acc = 0.f;
    for (int rr = rl; rr < RPS; rr += 4)
      acc += P[((size_t)g * RANKS + s * RPS + rr) * GCOLS + c];
    red[rl][c] = acc;
    __syncthreads();
    if (threadIdx.x < GCOLS) {
      float sum = 0.f;
      for (int r = 0; r < 4; ++r) sum += red[r][threadIdx.x];
      P2[(size_t)blockIdx.x * GCOLS + threadIdx.x] = sum;
    }
  } else {
    const int s  = blockIdx.x - S1BLK;   // 0..7
    const int b  = threadIdx.x & 127;
    const int rg = threadIdx.x >> 7;
    float acc = 0.f;
    for (int r = s + 8 * rg; r < hrows; r += 16)
      acc += hp[(size_t)r * BDIM + b];
    redh[rg][b] = acc;
    __syncthreads();
    if (threadIdx.x < BDIM)
      hp2[(size_t)s * BDIM + threadIdx.x] = redh[0][threadIdx.x] + redh[1][threadIdx.x];
  }
}

// ---------------------------------------------------------------------------
// Kernel 4: final: out[b] = sum_s hp2[s][b] + sum_s P2[(g*8+s)][c].
// ---------------------------------------------------------------------------
__global__ __launch_bounds__(128) void reduce2_kernel(
    const float* __restrict__ P2, const float* __restrict__ hp2,
    float* __restrict__ out) {
  const int b = threadIdx.x;
  const int g = b >> 6;
  const int c = b & 63;
  float acc = 0.f;
  for (int s = 0; s < 8; ++s) acc += hp2[(size_t)s * BDIM + b];
  for (int s = 0; s < 8; ++s) acc += P2[(size_t)(g * 8 + s) * GCOLS + c];
  out[b] = acc;
}

extern "C" void kernel_launch(void* const* d_in, const int* in_sizes, int n_in,
                              void* d_out, int out_size, void* d_ws, size_t ws_size,
                              hipStream_t stream) {
  const float* x  = (const float*)d_in[0];
  const float* h  = (const float*)d_in[1];
  const float* J  = (const float*)d_in[2];
  const int*   ei = (const int*)d_in[3];
  const int*   ej = (const int*)d_in[4];
  float* out = (float*)d_out;

  const int N = in_sizes[1];   // 50000
  const int E = in_sizes[2];   // 1600000

  const int tblocks = (N + 63) / 64;

  // ws layout: xTh (2*N*64 halves) | P (2048*64) | P2 (16*64) | hp (tblocks*128) | hp2 (8*128)
  __half* xTh = (__half*)d_ws;
  float* P   = (float*)(xTh + (size_t)NGROUPS * N * GCOLS);
  float* P2  = P   + (size_t)NGROUPS * RANKS * GCOLS;
  float* hp  = P2  + (size_t)S1BLK * GCOLS;
  float* hp2 = hp  + (size_t)tblocks * BDIM;

  // 1) transpose + fp16 convert + register-fused h-term partials
  transpose_h_kernel<<<tblocks, 256, 0, stream>>>(x, h, xTh, hp, N);

  // 2) edge interactions (R13 config — at the random-line wall)
  edge_kernel<<<EBLK, 256, 0, stream>>>(xTh, J, ei, ej, P, E, N);

  // 3) stage-1 reduce (edge partials + h partials)
  reduce1_kernel<<<S1BLK + HBLK2, 256, 0, stream>>>(P, hp, P2, hp2, tblocks);

  // 4) final deterministic reduce (overwrites d_out)
  reduce2_kernel<<<1, BDIM, 0, stream>>>(P2, hp2, out);
}